// Round 3
// baseline (528.282 us; speedup 1.0000x reference)
//
#include <hip/hip_runtime.h>

// PowerSpectrum: out[s,n, l*f^2 + i*f + j] = (2l+1)^{-1/2} * sum_m c_l[s,n,m,i]*c_l[s,n,m,j]
// f = 128, m-count = 2l+1 (1,3,5,7), S*N = 2000.
//
// R2 accounting: in_sizes are ELEMENT COUNTS (R1's bytes theory failed). Round-0's
// 523 us = ~335 us harness poison fill (2.097 GB @ 6.26 TB/s, inside the timed
// region) + ~188 us for four kernels (540 MB @ 2.9 TB/s). This round: one merged
// launch (single ramp/drain, each block writes its full 256 KB output region
// contiguously) + non-temporal stores (write-once stream, don't thrash L2).
// R3 fix: __builtin_nontemporal_store needs a clang ext_vector type, not float4.
// Kernel floor: (524 MB + 16 MB) / 6.3 TB/s ~= 86 us; predicted total ~430-460 us.

#define NFEAT 128

typedef float v4f __attribute__((ext_vector_type(4)));

__device__ __constant__ float kCg[4] = {
    1.0f,
    0.57735026918962576451f,   // 1/sqrt(3)
    0.44721359549995793928f,   // 1/sqrt(5)
    0.37796447300922722721f};  // 1/sqrt(7)

// One l-section: scl points at the NM x 128 staged tile, ob at out + l*128*128.
// Same fma order + trailing cg multiply as the round-0 (absmax 0.0) kernel.
template <int NM>
__device__ __forceinline__ void do_l(const float* __restrict__ scl, float cg,
                                     float* __restrict__ ob, int i0, int j4) {
  // B fragment: c[m][4*j4 .. 4*j4+3] in registers (max 7 float4 = 28 VGPRs)
  float4 b[NM];
#pragma unroll
  for (int m = 0; m < NM; ++m) b[m] = ((const float4*)scl)[m * 32 + j4];

#pragma unroll
  for (int k = 0; k < 16; ++k) {
    const int i = i0 + 8 * k;  // 4 waves cover 8 contiguous rows per pass
    float4 acc = {0.f, 0.f, 0.f, 0.f};
#pragma unroll
    for (int m = 0; m < NM; ++m) {
      const float a = scl[m * NFEAT + i];  // 2-address wave-broadcast LDS read
      acc.x += a * b[m].x;
      acc.y += a * b[m].y;
      acc.z += a * b[m].z;
      acc.w += a * b[m].w;
    }
    acc.x *= cg; acc.y *= cg; acc.z *= cg; acc.w *= cg;
    // Non-temporal 16B store: output stream is write-once, bypass cache retention.
    v4f v = {acc.x, acc.y, acc.z, acc.w};
    __builtin_nontemporal_store(v, (v4f*)(ob + i * NFEAT) + j4);
  }
}

__global__ __launch_bounds__(256) void ps_all(const float* __restrict__ c0,
                                              const float* __restrict__ c1,
                                              const float* __restrict__ c2,
                                              const float* __restrict__ c3,
                                              float* __restrict__ out) {
  // 16 m-rows total (1+3+5+7) x 128 floats = 8 KB
  __shared__ float sc[16 * NFEAT];

  const int sn  = blockIdx.x;
  const int tid = threadIdx.x;

  // Stage all four c-tiles: 512 float4 total, 2 per thread.
  // LDS rows: l0 -> row 0, l1 -> rows 1-3, l2 -> rows 4-8, l3 -> rows 9-15.
  {
    const float4* s0 = (const float4*)(c0 + (size_t)sn * (1 * NFEAT));
    const float4* s1 = (const float4*)(c1 + (size_t)sn * (3 * NFEAT));
    const float4* s2 = (const float4*)(c2 + (size_t)sn * (5 * NFEAT));
    const float4* s3 = (const float4*)(c3 + (size_t)sn * (7 * NFEAT));
    float4* d = (float4*)sc;
#pragma unroll
    for (int rep = 0; rep < 2; ++rep) {
      const int t = tid + rep * 256;
      float4 v;
      if (t < 32)       v = s0[t];
      else if (t < 128) v = s1[t - 32];
      else if (t < 288) v = s2[t - 128];
      else              v = s3[t - 288];
      d[t] = v;
    }
  }
  __syncthreads();

  const int j4 = tid & 31;   // float4 column 0..31  (j = 4*j4 .. 4*j4+3)
  const int i0 = tid >> 5;   // row phase 0..7

  float* obase = out + (size_t)sn * (4 * NFEAT * NFEAT);

  do_l<1>(sc + 0 * NFEAT, kCg[0], obase + 0 * NFEAT * NFEAT, i0, j4);
  do_l<3>(sc + 1 * NFEAT, kCg[1], obase + 1 * NFEAT * NFEAT, i0, j4);
  do_l<5>(sc + 4 * NFEAT, kCg[2], obase + 2 * NFEAT * NFEAT, i0, j4);
  do_l<7>(sc + 9 * NFEAT, kCg[3], obase + 3 * NFEAT * NFEAT, i0, j4);
}

extern "C" void kernel_launch(void* const* d_in, const int* in_sizes, int n_in,
                              void* d_out, int out_size, void* d_ws, size_t ws_size,
                              hipStream_t stream) {
  const float* c0 = (const float*)d_in[0];
  const float* c1 = (const float*)d_in[1];
  const float* c2 = (const float*)d_in[2];
  const float* c3 = (const float*)d_in[3];
  float* out = (float*)d_out;

  // in_sizes are ELEMENT counts: c_l0 is (S, N, 1, 128) f32 -> S*N = elems / 128.
  const int nsn = in_sizes[0] / NFEAT;

  dim3 block(256);
  dim3 grid(nsn);
  ps_all<<<grid, block, 0, stream>>>(c0, c1, c2, c3, out);
}